// Round 1
// baseline (10918.763 us; speedup 1.0000x reference)
//
#include <hip/hip_runtime.h>

#define VOCABN 50000
#define EMBD   256
#define HIDD   512
#define SEQL   512
#define BATCHN 128
#define KTOT   (EMBD + HIDD)   // 768

// One WG handles 2 batch rows for the entire sequence.
// 256 threads; thread t owns output columns (2t, 2t+1) of the hidden state.
// Pre-activation = [emb ; state] dot W[768][512] + b  (W = [Wx; Wh] as stored).
__global__ __launch_bounds__(256, 1)
void rnn_fused_f32(const int*   __restrict__ tokens,
                   const float* __restrict__ V,
                   const float* __restrict__ W,
                   const float* __restrict__ bias,
                   const float* __restrict__ Wd,
                   const float* __restrict__ bd,
                   float*       __restrict__ y)
{
    __shared__ float vcur[2][KTOT];   // [row][k]: k<256 = emb, k>=256 = state
    __shared__ int   toks[2][SEQL];
    __shared__ float red0[4], red1[4];

    const int tid  = threadIdx.x;        // 0..255
    const int c0   = tid * 2;            // column pair
    const int c1   = c0 + 1;
    const int row0 = blockIdx.x * 2;

    // stage this WG's tokens (2 rows x 512, contiguous) into LDS
    for (int i = tid; i < 2 * SEQL; i += 256) {
        toks[i >> 9][i & 511] = tokens[row0 * SEQL + i];
    }
    // init state part of vcur
    vcur[0][EMBD + c0] = 0.f; vcur[0][EMBD + c1] = 0.f;
    vcur[1][EMBD + c0] = 0.f; vcur[1][EMBD + c1] = 0.f;
    __syncthreads();

    // preload embedding for t=0 (thread tid handles emb element e=tid for both rows)
    float emb0 = V[(long)toks[0][0] * EMBD + tid];
    float emb1 = V[(long)toks[1][0] * EMBD + tid];

    const float bh0 = bias[c0], bh1 = bias[c1];
    float s00 = 0.f, s01 = 0.f, s10 = 0.f, s11 = 0.f;   // s[row][col]

    for (int t = 0; t < SEQL; ++t) {
        // publish embeddings for step t
        vcur[0][tid] = emb0;
        vcur[1][tid] = emb1;
        __syncthreads();   // (A) emb(t) + state(t-1) fully visible

        // prefetch embeddings for t+1 (latency hidden under the matvec)
        if (t + 1 < SEQL) {
            emb0 = V[(long)toks[0][t + 1] * EMBD + tid];
            emb1 = V[(long)toks[1][t + 1] * EMBD + tid];
        }

        // matvec: acc[row][col] over k=0..767
        float a000 = 0.f, a001 = 0.f, a010 = 0.f, a011 = 0.f;  // k-offset group 0
        float a100 = 0.f, a101 = 0.f, a110 = 0.f, a111 = 0.f;  // k-offset group 1
        const float* Wp = W + c0;
        #pragma unroll 4
        for (int k = 0; k < KTOT; k += 4) {
            const float4 v0 = *(const float4*)(&vcur[0][k]);   // LDS broadcast
            const float4 v1 = *(const float4*)(&vcur[1][k]);
            const float2 w0 = *(const float2*)(Wp + (size_t)(k + 0) * HIDD);
            const float2 w1 = *(const float2*)(Wp + (size_t)(k + 1) * HIDD);
            const float2 w2 = *(const float2*)(Wp + (size_t)(k + 2) * HIDD);
            const float2 w3 = *(const float2*)(Wp + (size_t)(k + 3) * HIDD);
            a000 = fmaf(v0.x, w0.x, a000);  a001 = fmaf(v0.x, w0.y, a001);
            a010 = fmaf(v1.x, w0.x, a010);  a011 = fmaf(v1.x, w0.y, a011);
            a100 = fmaf(v0.y, w1.x, a100);  a101 = fmaf(v0.y, w1.y, a101);
            a110 = fmaf(v1.y, w1.x, a110);  a111 = fmaf(v1.y, w1.y, a111);
            a000 = fmaf(v0.z, w2.x, a000);  a001 = fmaf(v0.z, w2.y, a001);
            a010 = fmaf(v1.z, w2.x, a010);  a011 = fmaf(v1.z, w2.y, a011);
            a100 = fmaf(v0.w, w3.x, a100);  a101 = fmaf(v0.w, w3.y, a101);
            a110 = fmaf(v1.w, w3.x, a110);  a111 = fmaf(v1.w, w3.y, a111);
        }
        s00 = tanhf(bh0 + a000 + a100);
        s01 = tanhf(bh1 + a001 + a101);
        s10 = tanhf(bh0 + a010 + a110);
        s11 = tanhf(bh1 + a011 + a111);

        __syncthreads();   // (B) all reads of old state/emb done before overwrite
        vcur[0][EMBD + c0] = s00; vcur[0][EMBD + c1] = s01;
        vcur[1][EMBD + c0] = s10; vcur[1][EMBD + c1] = s11;
        // next iteration's barrier (A) orders these writes before the next matvec
    }

    // final: y[row] = state . Wd + bd  (states for our columns still in registers)
    const float wd0 = Wd[c0], wd1 = Wd[c1];
    float q0 = s00 * wd0 + s01 * wd1;   // row0 partial
    float q1 = s10 * wd0 + s11 * wd1;   // row1 partial
    for (int off = 32; off > 0; off >>= 1) {
        q0 += __shfl_down(q0, off);
        q1 += __shfl_down(q1, off);
    }
    const int wv = tid >> 6, ln = tid & 63;
    if (ln == 0) { red0[wv] = q0; red1[wv] = q1; }
    __syncthreads();
    if (tid == 0) {
        const float bdv = bd[0];
        y[row0 + 0] = red0[0] + red0[1] + red0[2] + red0[3] + bdv;
        y[row0 + 1] = red1[0] + red1[1] + red1[2] + red1[3] + bdv;
    }
}

extern "C" void kernel_launch(void* const* d_in, const int* in_sizes, int n_in,
                              void* d_out, int out_size, void* d_ws, size_t ws_size,
                              hipStream_t stream)
{
    const int*   tokens = (const int*)  d_in[0];
    const float* V      = (const float*)d_in[1];
    const float* W      = (const float*)d_in[2];
    const float* b      = (const float*)d_in[3];
    const float* Wd     = (const float*)d_in[4];
    const float* bd     = (const float*)d_in[5];
    float* y = (float*)d_out;

    hipLaunchKernelGGL(rnn_fused_f32, dim3(BATCHN / 2), dim3(256), 0, stream,
                       tokens, V, W, b, Wd, bd, y);
}

// Round 2
// 5662.838 us; speedup vs baseline: 1.9281x; 1.9281x over previous
//
#include <hip/hip_runtime.h>

#define EMBD 256
#define HIDD 512
#define SEQL 512
#define KTOT 768          // EMB + HID
#define KP   384          // k-pairs
#define NCOL 512

typedef unsigned int u32;
typedef _Float16 h2 __attribute__((ext_vector_type(2)));

static __device__ __forceinline__ float dot2(u32 a, u32 b, float c) {
#if __has_builtin(__builtin_amdgcn_fdot2)
    return __builtin_amdgcn_fdot2(__builtin_bit_cast(h2, a), __builtin_bit_cast(h2, b), c, false);
#else
    h2 ha = __builtin_bit_cast(h2, a), hb = __builtin_bit_cast(h2, b);
    float r = fmaf((float)ha.x, (float)hb.x, c);
    return fmaf((float)ha.y, (float)hb.y, r);
#endif
}

static __device__ __forceinline__ u32 packh2(float a, float b) {
    _Float16 lo = (_Float16)a, hi = (_Float16)b;
    return (u32)__builtin_bit_cast(unsigned short, lo)
         | ((u32)__builtin_bit_cast(unsigned short, hi) << 16);
}

// Pack W (f32 [768][512]) -> W16 (dword [384][512]): dword(kp,c) = (h(W[2kp][c]), h(W[2kp+1][c]))
__global__ __launch_bounds__(256)
void convert_W(const float* __restrict__ W, u32* __restrict__ W16) {
    int idx = blockIdx.x * 256 + threadIdx.x;
    if (idx >= KP * NCOL) return;
    int kp = idx >> 9, c = idx & 511;
    float lo = W[(size_t)(2 * kp) * NCOL + c];
    float hi = W[(size_t)(2 * kp + 1) * NCOL + c];
    W16[idx] = packh2(lo, hi);
}

// One WG = 2 batch rows, 1024 threads = 16 waves (4/SIMD).
// tid = ks*256 + t : ks = k-split (0..3, 192 k each), t -> cols (2t, 2t+1).
__global__ __launch_bounds__(1024)
void rnn_fused_h16(const int*   __restrict__ tokens,
                   const float* __restrict__ V,
                   const u32*   __restrict__ W16,
                   const float* __restrict__ bias,
                   const float* __restrict__ Wd,
                   const float* __restrict__ bd,
                   float*       __restrict__ y)
{
    __shared__ __align__(16) u32 vcur4[2][KP];   // halves [2][768]: [0..255]=emb, [256..767]=state
    __shared__ float part[8][NCOL];              // [ks*2 + row][col]
    __shared__ int   toks[2][SEQL];
    __shared__ float red[16];

    const int tid  = threadIdx.x;
    const int ks   = tid >> 8;          // 0..3
    const int t8   = tid & 255;
    const int c0   = t8 * 2;
    const int row0 = blockIdx.x * 2;

    const int r_e = (tid >> 7) & 1;     // emb prefetch role (tid<256)
    const int e2  = tid & 127;
    const int r4  = tid >> 9;           // phase-4 role: (row, col)
    const int c4  = tid & 511;

    // stage tokens (2 x 512)
    toks[tid >> 9][tid & 511] = tokens[row0 * SEQL + tid];
    // zero the state part of vcur
    if (tid < 512) vcur4[tid >> 8][128 + (tid & 255)] = 0u;
    __syncthreads();

    // prologue: emb(0)
    if (tid < 256) {
        int tok = toks[r_e][0];
        float2 ev = *(const float2*)&V[(size_t)tok * EMBD + 2 * e2];
        vcur4[r_e][e2] = packh2(ev.x, ev.y);
    }
    __syncthreads();

    const float bh = bias[c4];
    float s_final = 0.f;
    u32 embreg = 0u;

    for (int t = 0; t < SEQL; ++t) {
        // ---- phase 1: partial matvec over this thread's 96 k-pairs ----
        float a00 = 0.f, a01 = 0.f, a10 = 0.f, a11 = 0.f;
        const u32* Wp  = W16 + (size_t)(ks * 96) * NCOL + c0;
        const u32* v0p = &vcur4[0][ks * 96];
        const u32* v1p = &vcur4[1][ks * 96];

        // prefetch next embedding under the matvec
        if (tid < 256 && t + 1 < SEQL) {
            int tok = toks[r_e][t + 1];
            float2 ev = *(const float2*)&V[(size_t)tok * EMBD + 2 * e2];
            embreg = packh2(ev.x, ev.y);
        }

        #pragma unroll 4
        for (int kb = 0; kb < 96; kb += 4) {
            uint4 v0 = *(const uint4*)(v0p + kb);   // 4 k-pairs, row 0 (LDS broadcast)
            uint4 v1 = *(const uint4*)(v1p + kb);   // 4 k-pairs, row 1
            uint2 w0 = *(const uint2*)(Wp + (size_t)(kb + 0) * NCOL);
            uint2 w1 = *(const uint2*)(Wp + (size_t)(kb + 1) * NCOL);
            uint2 w2 = *(const uint2*)(Wp + (size_t)(kb + 2) * NCOL);
            uint2 w3 = *(const uint2*)(Wp + (size_t)(kb + 3) * NCOL);
            a00 = dot2(v0.x, w0.x, a00);  a01 = dot2(v0.x, w0.y, a01);
            a10 = dot2(v1.x, w0.x, a10);  a11 = dot2(v1.x, w0.y, a11);
            a00 = dot2(v0.y, w1.x, a00);  a01 = dot2(v0.y, w1.y, a01);
            a10 = dot2(v1.y, w1.x, a10);  a11 = dot2(v1.y, w1.y, a11);
            a00 = dot2(v0.z, w2.x, a00);  a01 = dot2(v0.z, w2.y, a01);
            a10 = dot2(v1.z, w2.x, a10);  a11 = dot2(v1.z, w2.y, a11);
            a00 = dot2(v0.w, w3.x, a00);  a01 = dot2(v0.w, w3.y, a01);
            a10 = dot2(v1.w, w3.x, a10);  a11 = dot2(v1.w, w3.y, a11);
        }

        // ---- phase 2: publish partials ----
        *(float2*)&part[ks * 2 + 0][c0] = make_float2(a00, a01);
        *(float2*)&part[ks * 2 + 1][c0] = make_float2(a10, a11);
        __syncthreads();   // B1: all vcur reads done, partials visible

        // ---- phase 4: reduce + tanh + publish state(t), emb(t+1) ----
        float sum = part[r4][c4] + part[2 + r4][c4] + part[4 + r4][c4] + part[6 + r4][c4];
        float s = tanhf(sum + bh);
        s_final = s;
        ((_Float16*)vcur4)[r4 * KTOT + EMBD + c4] = (_Float16)s;
        if (tid < 256 && t + 1 < SEQL) vcur4[r_e][e2] = embreg;
        __syncthreads();   // B2: new v visible for next step
    }

    // ---- epilogue: y[row] = state . Wd + bd ----
    float q = s_final * Wd[c4];
    for (int off = 32; off > 0; off >>= 1) q += __shfl_down(q, off);
    const int wv = tid >> 6, ln = tid & 63;
    if (ln == 0) red[wv] = q;
    __syncthreads();
    if (tid == 0) {
        float s0 = 0.f, s1 = 0.f;
        #pragma unroll
        for (int i = 0; i < 8; ++i)  s0 += red[i];
        #pragma unroll
        for (int i = 8; i < 16; ++i) s1 += red[i];
        y[row0 + 0] = s0 + bd[0];
        y[row0 + 1] = s1 + bd[0];
    }
}

extern "C" void kernel_launch(void* const* d_in, const int* in_sizes, int n_in,
                              void* d_out, int out_size, void* d_ws, size_t ws_size,
                              hipStream_t stream)
{
    const int*   tokens = (const int*)  d_in[0];
    const float* V      = (const float*)d_in[1];
    const float* W      = (const float*)d_in[2];
    const float* b      = (const float*)d_in[3];
    const float* Wd     = (const float*)d_in[4];
    const float* bd     = (const float*)d_in[5];
    float* y   = (float*)d_out;
    u32*   W16 = (u32*)d_ws;            // 384*512*4 = 768 KB

    hipLaunchKernelGGL(convert_W, dim3((KP * NCOL + 255) / 256), dim3(256), 0, stream, W, W16);
    hipLaunchKernelGGL(rnn_fused_h16, dim3(64), dim3(1024), 0, stream,
                       tokens, V, W16, b, Wd, bd, y);
}

// Round 3
// 1492.681 us; speedup vs baseline: 7.3149x; 3.7937x over previous
//
#include <hip/hip_runtime.h>

#define EMBD 256
#define HIDD 512
#define SEQL 512
#define KTOT 768
#define KP   384          // h2-packed dwords per input row
#define NCOL 512
#define RG_ROWS 4
#define NRG  32           // row groups
#define NCG  8            // col groups (WGs per row group)
#define CGC  64           // cols per WG
#define NWG  (NRG * NCG)  // 256
#define THR  512

typedef unsigned int u32;
typedef unsigned long long u64;
typedef _Float16 h2 __attribute__((ext_vector_type(2)));

#define WS_W16_OFF  0
#define WS_CTR_OFF  (768 * 1024)
#define WS_X_OFF    (768 * 1024 + 4096)
// X[2][NRG][1024 dwords] : per row-group state, h2-packed: d = r*256 + colpair

static __device__ __forceinline__ float dot2(u32 a, u32 b, float c) {
#if __has_builtin(__builtin_amdgcn_fdot2)
    return __builtin_amdgcn_fdot2(__builtin_bit_cast(h2, a), __builtin_bit_cast(h2, b), c, false);
#else
    h2 ha = __builtin_bit_cast(h2, a), hb = __builtin_bit_cast(h2, b);
    float r = fmaf((float)ha.x, (float)hb.x, c);
    return fmaf((float)ha.y, (float)hb.y, r);
#endif
}

static __device__ __forceinline__ u32 packh2(float a, float b) {
    _Float16 lo = (_Float16)a, hi = (_Float16)b;
    return (u32)__builtin_bit_cast(unsigned short, lo)
         | ((u32)__builtin_bit_cast(unsigned short, hi) << 16);
}

__global__ __launch_bounds__(1024)
void init_ctr(u32* __restrict__ ctr) {
    ctr[threadIdx.x] = 0u;   // 1024 dwords: 32 rg x 32-dword stride
}

// W (f32 [768][512]) -> W16 (dword [384][512]): dword(kp,c) = (h(W[2kp][c]), h(W[2kp+1][c]))
__global__ __launch_bounds__(256)
void convert_W(const float* __restrict__ W, u32* __restrict__ W16) {
    int idx = blockIdx.x * 256 + threadIdx.x;
    if (idx >= KP * NCOL) return;
    int kp = idx >> 9, c = idx & 511;
    float lo = W[(size_t)(2 * kp) * NCOL + c];
    float hi = W[(size_t)(2 * kp + 1) * NCOL + c];
    W16[idx] = packh2(lo, hi);
}

// 256 WGs x 512 threads. WG (rg,cg): rows rg*4..+3, cols cg*64..+63.
// Thread: ks = tid>>6 (48 k-pairs), lane = tid&63 (1 col). W slice in 48 VGPRs.
__global__ __launch_bounds__(THR, 1)
void rnn_coop(const int*   __restrict__ tokens,
              const float* __restrict__ V,
              const u32*   __restrict__ W16,
              const float* __restrict__ bias,
              const float* __restrict__ Wd,
              const float* __restrict__ bd,
              float*       __restrict__ y,
              u32*         __restrict__ ctr,
              u32*         __restrict__ X)
{
    __shared__ __align__(16) u32 vcur[RG_ROWS][KP];      // 6 KB: [0..127]=emb, [128..383]=state
    __shared__ float part[RG_ROWS][CGC][9];              // 9 KB, pad 9 to dodge bank conflicts
    __shared__ int   toks[RG_ROWS][SEQL];                // 8 KB
    __shared__ float yred[8];

    const int tid  = threadIdx.x;
    const int wg   = blockIdx.x;
    const int rg   = wg >> 3;
    const int cg   = wg & 7;
    const int ks   = tid >> 6;           // 0..7
    const int lane = tid & 63;
    const int gc   = cg * CGC + lane;    // global col
    const int row0 = rg * RG_ROWS;

    // stage tokens for our 4 rows
    for (int i = tid; i < RG_ROWS * SEQL; i += THR)
        toks[i >> 9][i & 511] = tokens[(row0 + (i >> 9)) * SEQL + (i & 511)];
    // zero state region of vcur
    for (int i = tid; i < RG_ROWS * 256; i += THR)
        vcur[i >> 8][128 + (i & 255)] = 0u;

    // W slice into registers: w[i] = W16[(ks*48+i)*512 + gc]
    u32 w[48];
    #pragma unroll
    for (int i = 0; i < 48; ++i)
        w[i] = W16[(size_t)(ks * 48 + i) * NCOL + gc];

    __syncthreads();

    // emb(0): thread -> (row er, pair ee)
    const int er = tid >> 7, ee = tid & 127;
    {
        int tok = toks[er][0];
        float2 ev = *(const float2*)&V[(size_t)tok * EMBD + 2 * ee];
        vcur[er][ee] = packh2(ev.x, ev.y);
    }
    __syncthreads();

    const float bias_r = (tid < 256) ? bias[cg * CGC + (tid & 63)] : 0.f;
    u32* const  myctr  = ctr + rg * 32;

    for (int t = 0; t < SEQL; ++t) {
        // ---- emb(t+1) prefetch (pack deferred to phase B) ----
        int tn = (t + 1 < SEQL) ? (t + 1) : (SEQL - 1);
        int tokn = toks[er][tn];
        float2 ev = *(const float2*)&V[(size_t)tokn * EMBD + 2 * ee];

        // ---- matvec: acc[r] over our 48 k-pairs, col gc ----
        float acc0 = 0.f, acc1 = 0.f, acc2 = 0.f, acc3 = 0.f;
        const uint4* vb = (const uint4*)vcur;   // [4][96]
        const int kb = ks * 12;
        #pragma unroll
        for (int j = 0; j < 12; ++j) {
            uint4 a0 = vb[0 * 96 + kb + j];     // wave-uniform broadcast reads
            uint4 a1 = vb[1 * 96 + kb + j];
            uint4 a2 = vb[2 * 96 + kb + j];
            uint4 a3 = vb[3 * 96 + kb + j];
            acc0 = dot2(a0.x, w[4*j+0], acc0); acc0 = dot2(a0.y, w[4*j+1], acc0);
            acc0 = dot2(a0.z, w[4*j+2], acc0); acc0 = dot2(a0.w, w[4*j+3], acc0);
            acc1 = dot2(a1.x, w[4*j+0], acc1); acc1 = dot2(a1.y, w[4*j+1], acc1);
            acc1 = dot2(a1.z, w[4*j+2], acc1); acc1 = dot2(a1.w, w[4*j+3], acc1);
            acc2 = dot2(a2.x, w[4*j+0], acc2); acc2 = dot2(a2.y, w[4*j+1], acc2);
            acc2 = dot2(a2.z, w[4*j+2], acc2); acc2 = dot2(a2.w, w[4*j+3], acc2);
            acc3 = dot2(a3.x, w[4*j+0], acc3); acc3 = dot2(a3.y, w[4*j+1], acc3);
            acc3 = dot2(a3.z, w[4*j+2], acc3); acc3 = dot2(a3.w, w[4*j+3], acc3);
        }
        part[0][lane][ks] = acc0;
        part[1][lane][ks] = acc1;
        part[2][lane][ks] = acc2;
        part[3][lane][ks] = acc3;
        __syncthreads();   // B1: partials visible, vcur reads done

        // ---- phase B: reduce + tanh + publish slice; emb(t+1) -> vcur ----
        if (tid < 256) {
            const int rr = tid >> 6, rc = tid & 63;
            float s = part[rr][rc][0] + part[rr][rc][1] + part[rr][rc][2] + part[rr][rc][3]
                    + part[rr][rc][4] + part[rr][rc][5] + part[rr][rc][6] + part[rr][rc][7]
                    + bias_r;
            s = tanhf(s);
            float snb = __shfl_down(s, 1);
            if ((rc & 1) == 0) {
                u32 dw = packh2(s, snb);
                u32* p = X + ((size_t)(t & 1) * NRG + rg) * 1024
                           + rr * 256 + cg * 32 + (rc >> 1);
                __hip_atomic_store(p, dw, __ATOMIC_RELAXED, __HIP_MEMORY_SCOPE_AGENT);
            }
        }
        vcur[er][ee] = packh2(ev.x, ev.y);
        __syncthreads();   // B2: drains vmcnt -> slice stores globally visible

        // ---- inter-WG barrier (8 WGs of this row group) ----
        if (tid == 0) {
            __hip_atomic_fetch_add(myctr, 1u, __ATOMIC_RELAXED, __HIP_MEMORY_SCOPE_AGENT);
            const u32 target = 8u * (u32)(t + 1);
            while (__hip_atomic_load(myctr, __ATOMIC_RELAXED, __HIP_MEMORY_SCOPE_AGENT) < target)
                __builtin_amdgcn_s_sleep(1);
        }
        __syncthreads();   // B3

        // ---- read full state(t) for our 4 rows into vcur ----
        {
            const u64* Xr = (const u64*)(X + ((size_t)(t & 1) * NRG + rg) * 1024);
            u64 two = __hip_atomic_load(Xr + tid, __ATOMIC_RELAXED, __HIP_MEMORY_SCOPE_AGENT);
            const int r = tid >> 7, cp = (2 * tid) & 255;
            *(u64*)&vcur[r][128 + cp] = two;
        }
        __syncthreads();   // B4: vcur ready for next step
    }

    // ---- epilogue: cg==0 WGs compute y for their 4 rows ----
    if (cg == 0) {
        const int r = tid >> 7, q = tid & 127;
        u32 dA = vcur[r][128 + 2 * q], dB = vcur[r][128 + 2 * q + 1];
        h2 a = __builtin_bit_cast(h2, dA), b = __builtin_bit_cast(h2, dB);
        float p = (float)a.x * Wd[4 * q + 0] + (float)a.y * Wd[4 * q + 1]
                + (float)b.x * Wd[4 * q + 2] + (float)b.y * Wd[4 * q + 3];
        #pragma unroll
        for (int off = 32; off > 0; off >>= 1) p += __shfl_down(p, off);
        if ((tid & 63) == 0) yred[tid >> 6] = p;
        __syncthreads();
        if (tid < 4) y[row0 + tid] = yred[2 * tid] + yred[2 * tid + 1] + bd[0];
    }
}

extern "C" void kernel_launch(void* const* d_in, const int* in_sizes, int n_in,
                              void* d_out, int out_size, void* d_ws, size_t ws_size,
                              hipStream_t stream)
{
    const int*   tokens = (const int*)  d_in[0];
    const float* V      = (const float*)d_in[1];
    const float* W      = (const float*)d_in[2];
    const float* b      = (const float*)d_in[3];
    const float* Wd     = (const float*)d_in[4];
    const float* bd     = (const float*)d_in[5];
    float* y = (float*)d_out;

    u32* W16 = (u32*)((char*)d_ws + WS_W16_OFF);
    u32* ctr = (u32*)((char*)d_ws + WS_CTR_OFF);
    u32* X   = (u32*)((char*)d_ws + WS_X_OFF);

    hipLaunchKernelGGL(init_ctr, dim3(1), dim3(1024), 0, stream, ctr);
    hipLaunchKernelGGL(convert_W, dim3((KP * NCOL + 255) / 256), dim3(256), 0, stream, W, W16);
    hipLaunchKernelGGL(rnn_coop, dim3(NWG), dim3(THR), 0, stream,
                       tokens, V, W16, b, Wd, bd, y, ctr, X);
}